// Round 15
// baseline (343.228 us; speedup 1.0000x reference)
//
#include <hip/hip_runtime.h>
#include <hip/hip_bf16.h>

// B=2, S=2048, HID=1024, NH=16, HD=64
#define B_    2
#define S_    2048
#define HID_  1024
#define NH_   16
#define HD_   64
#define M_    (B_ * S_)          // 4096 rows
#define NEGB_ (-1.0e30f)         // mask bias in log2 domain; exp2 -> 0
#define LOG2E 1.44269504088896340736f
#define X_ELEMS 4194304          // B*S*HID
#define BH_   (B_ * NH_)         // 32

typedef __bf16 bf16;
typedef bf16  bf16x2 __attribute__((ext_vector_type(2)));
typedef bf16  bf16x4 __attribute__((ext_vector_type(4)));
typedef bf16  bf16x8 __attribute__((ext_vector_type(8)));
typedef float f32x4  __attribute__((ext_vector_type(4)));

static __device__ __forceinline__ f32x4 mfma16(bf16x8 a, bf16x8 b, f32x4 c) {
    return __builtin_amdgcn_mfma_f32_16x16x32_bf16(a, b, c, 0, 0, 0);
}

static __device__ __forceinline__ int pack2(float x, float y) {
    union { bf16x2 h; int i; } u;
    u.h = bf16x2{(bf16)x, (bf16)y};
    return u.i;
}

// LDS-only barrier: drains ds ops but leaves global loads/stores in flight.
static __device__ __forceinline__ void barrier_lds() {
    asm volatile("s_waitcnt lgkmcnt(0)" ::: "memory");
    __builtin_amdgcn_s_barrier();
}

// swizzled LDS byte address for [row][chunk16B] tiles with 128B row stride
static __device__ __forceinline__ int swadr(int row, int chunk) {
    return row * 128 + ((chunk ^ (row & 7)) << 4);
}
static __device__ __forceinline__ bf16x8 lds8(const bf16* base, int row, int chunk) {
    return *(const bf16x8*)((const char*)base + swadr(row, chunk));
}

// ---------------- prep kernels ----------------

__global__ void cast3(const float* __restrict__ a, const float* __restrict__ b,
                      const float* __restrict__ c, bf16* __restrict__ oa,
                      bf16* __restrict__ ob, bf16* __restrict__ oc) {
    const float* in = blockIdx.y == 0 ? a : blockIdx.y == 1 ? b : c;
    bf16* out = blockIdx.y == 0 ? oa : blockIdx.y == 1 ? ob : oc;
    int i = (blockIdx.x * 256 + threadIdx.x) * 4;
    float4 v = *(const float4*)(in + i);
    out[i + 0] = (bf16)v.x;
    out[i + 1] = (bf16)v.y;
    out[i + 2] = (bf16)v.z;
    out[i + 3] = (bf16)v.w;
}

// Wq_eff[h*64+j][i] = LOG2E * sum_d Ww[j][d] * Wq[h*64+d][i]; also bq_eff.
__global__ __launch_bounds__(256) void fuse_wq(const float* __restrict__ Ww,
                                               const float* __restrict__ Wq,
                                               const float* __restrict__ bq,
                                               const float* __restrict__ bw,
                                               bf16* __restrict__ Wq_eff,
                                               float* __restrict__ bq_eff) {
    __shared__ float ww[64][64];
    const int h = blockIdx.x >> 2, chunk = blockIdx.x & 3;
    const int i = chunk * 256 + threadIdx.x;
    for (int t = threadIdx.x; t < 4096; t += 256) ww[t >> 6][t & 63] = Ww[t];
    __syncthreads();
    float col[64];
    #pragma unroll
    for (int d = 0; d < 64; ++d) col[d] = Wq[(size_t)(h * 64 + d) * 1024 + i];
    for (int j = 0; j < 64; ++j) {
        float acc = 0.f;
        #pragma unroll
        for (int d = 0; d < 64; ++d) acc += ww[j][d] * col[d];
        Wq_eff[(size_t)(h * 64 + j) * 1024 + i] = (bf16)(acc * LOG2E);
    }
    if (chunk == 0 && threadIdx.x < 64) {
        int j = threadIdx.x;
        float acc = bw[j];
        for (int d = 0; d < 64; ++d) acc += ww[j][d] * bq[h * 64 + d];
        bq_eff[h * 64 + j] = acc * LOG2E;
    }
}

// ---------------- QKV projections: LDS-staged GEMM, BM=128 BN=128 BK=64 ----------------
__global__ __launch_bounds__(256, 2) void proj3(const float* __restrict__ Aq,
                                                const float* __restrict__ Ak,
                                                const float* __restrict__ Av,
                                                const bf16* __restrict__ W0,
                                                const bf16* __restrict__ W1,
                                                const bf16* __restrict__ W2,
                                                const float* __restrict__ b0,
                                                const float* __restrict__ b1,
                                                const float* __restrict__ b2,
                                                bf16* __restrict__ Qw,
                                                bf16* __restrict__ Kh,
                                                bf16* __restrict__ Vt) {
    __shared__ __align__(16) bf16 Ast[2][128 * 64];   // 2 x 16 KB
    __shared__ __align__(16) bf16 Wst[2][128 * 64];   // 2 x 16 KB
    const int z = blockIdx.z;
    const float* A = z == 0 ? Aq : z == 1 ? Ak : Av;
    const bf16* W = z == 0 ? W0 : z == 1 ? W1 : W2;
    const float* bias = z == 0 ? b0 : z == 1 ? b1 : b2;

    const int tid = threadIdx.x;
    const int wave = tid >> 6, lane = tid & 63;
    const int lr = lane & 15, kg = lane >> 4;
    const int mb0 = blockIdx.x * 128;
    const int n0 = blockIdx.y * 128;

    const int arow = tid >> 1, akc = (tid & 1) * 32;   // A: 128 rows x 2 half-rows (f32)
    const int wrow = tid >> 1, wkc = (tid & 1) * 32;   // W: 128 rows x 2 half-rows (bf16)

    float4 ar[8];
    bf16x8 wr[4];
    auto loadT = [&](int k0) {
        const float4* ap = (const float4*)(A + (size_t)(mb0 + arow) * HID_ + k0 + akc);
        #pragma unroll
        for (int j = 0; j < 8; ++j) ar[j] = ap[j];
        const bf16* wp = W + (size_t)(n0 + wrow) * HID_ + k0 + wkc;
        #pragma unroll
        for (int j = 0; j < 4; ++j) wr[j] = *(const bf16x8*)(wp + j * 8);
    };
    auto writeT = [&](int buf) {
        #pragma unroll
        for (int c = 0; c < 4; ++c) {
            float4 x0 = ar[2 * c], x1 = ar[2 * c + 1];
            bf16x8 v;
            v[0] = (bf16)x0.x; v[1] = (bf16)x0.y; v[2] = (bf16)x0.z; v[3] = (bf16)x0.w;
            v[4] = (bf16)x1.x; v[5] = (bf16)x1.y; v[6] = (bf16)x1.z; v[7] = (bf16)x1.w;
            *(bf16x8*)((char*)Ast[buf] + swadr(arow, (akc >> 3) + c)) = v;
        }
        #pragma unroll
        for (int c = 0; c < 4; ++c)
            *(bf16x8*)((char*)Wst[buf] + swadr(wrow, (wkc >> 3) + c)) = wr[c];
    };

    f32x4 acc[2][8] = {};
    loadT(0);
    for (int t = 0; t < 16; ++t) {
        const int buf = t & 1;
        writeT(buf);
        if (t < 15) loadT((t + 1) * 64);
        barrier_lds();
        const bf16* ab = Ast[buf];
        const bf16* wb = Wst[buf];
        #pragma unroll
        for (int kp = 0; kp < 2; ++kp) {
            bf16x8 af0 = lds8(ab, wave * 16 + lr, kp * 4 + kg);
            bf16x8 af1 = lds8(ab, 64 + wave * 16 + lr, kp * 4 + kg);
            #pragma unroll
            for (int nf = 0; nf < 8; ++nf) {
                bf16x8 wf = lds8(wb, nf * 16 + lr, kp * 4 + kg);
                acc[0][nf] = mfma16(af0, wf, acc[0][nf]);
                acc[1][nf] = mfma16(af1, wf, acc[1][nf]);
            }
        }
        barrier_lds();
    }

    const int m_base = mb0 + wave * 16;
    #pragma unroll
    for (int t = 0; t < 2; ++t) {
        #pragma unroll
        for (int cg = 0; cg < 8; ++cg) {
            int col = n0 + cg * 16 + lr;
            float bv = bias[col];
            int h = col >> 6, d = col & 63;
            #pragma unroll
            for (int r = 0; r < 4; ++r) {
                int m = m_base + t * 64 + kg * 4 + r;
                int b = m >> 11, s = m & 2047;
                float val = acc[t][cg][r] + bv;
                if (z == 0)
                    Qw[((size_t)(b * NH_ + h) * S_ + s) * HD_ + d] = (bf16)val;
                else if (z == 1)
                    Kh[((size_t)(b * NH_ + h) * S_ + s) * HD_ + d] = (bf16)val;
                else
                    Vt[((size_t)(b * NH_ + h) * HD_ + d) * S_ + s] = (bf16)val;
            }
        }
    }
}

// ---------------- attn part 1: partial row sums over a kv half ----------------
// 1024 blocks x 512 thr: (bh, qtile, half). Each block sums 16 kv tiles.
__global__ __launch_bounds__(512, 8) void attn_sums(const bf16* __restrict__ Qw,
                                                    const bf16* __restrict__ Kh,
                                                    const int* __restrict__ mask,
                                                    float* __restrict__ lsum_g) {
    __shared__ __align__(16) float negf[S_ / 2];  // 4 KB (this half's kv)
    __shared__ __align__(16) bf16 Kst[2][4096];   // 16 KB

    const int tid = threadIdx.x;
    const int lane = tid & 63, wave = tid >> 6;
    const int lr = lane & 15, kg = lane >> 4;

    const int wg = blockIdx.x;                    // 1024 blocks, 8-XCD bijective swizzle
    const int flat = (wg & 7) * 128 + (wg >> 3);
    const int half = flat & 1;
    const int qtile = (flat >> 1) & 15;
    const int bh = flat >> 5;
    const int b = bh >> 4;
    const int q0 = qtile * 128 + wave * 16;
    const int kv0 = half * (S_ / 2);

    const bf16* Qh = Qw + (size_t)bh * S_ * HD_;
    const bf16* Kb = Kh + (size_t)bh * S_ * HD_;
    const int*  mb = mask + b * S_ + kv0;

    for (int t = tid; t < S_ / 2; t += 512)
        negf[t] = mb[t] ? 0.f : NEGB_;

    const int srow = tid >> 3;                    // 0..63
    const int sch  = tid & 7;                     // 0..7
    const int sdst = swadr(srow, sch);

    bf16x8 a0 = *(const bf16x8*)(Qh + (size_t)(q0 + lr) * HD_ + kg * 8);
    bf16x8 a1 = *(const bf16x8*)(Qh + (size_t)(q0 + lr) * HD_ + 32 + kg * 8);

    __syncthreads();   // negf ready

    bf16x8 kreg = *(const bf16x8*)(Kb + (size_t)(kv0 + srow) * HD_ + sch * 8);

    float psum = 0.f;
    for (int t = 0; t < 16; ++t) {
        const int buf = t & 1;
        *(bf16x8*)((char*)Kst[buf] + sdst) = kreg;
        if (t + 1 < 16)
            kreg = *(const bf16x8*)(Kb + (size_t)(kv0 + (t + 1) * 64 + srow) * HD_ + sch * 8);
        barrier_lds();
        const bf16* kb = Kst[buf];
        #pragma unroll
        for (int s2 = 0; s2 < 2; ++s2) {
            const int rlo = s2 * 32 + lr, rhi = s2 * 32 + 16 + lr;
            bf16x8 k0a = lds8(kb, rlo, kg);
            bf16x8 k1a = lds8(kb, rlo, 4 + kg);
            bf16x8 k0b = lds8(kb, rhi, kg);
            bf16x8 k1b = lds8(kb, rhi, 4 + kg);
            f32x4 e0 = *(const f32x4*)&negf[t * 64 + s2 * 32 + kg * 4];
            f32x4 e1 = *(const f32x4*)&negf[t * 64 + s2 * 32 + 16 + kg * 4];
            e0 = mfma16(k0a, a0, e0);
            e0 = mfma16(k1a, a1, e0);
            e1 = mfma16(k0b, a0, e1);
            e1 = mfma16(k1b, a1, e1);
            #pragma unroll
            for (int r = 0; r < 4; ++r)
                psum += exp2f(e0[r]) + exp2f(e1[r]);
        }
        barrier_lds();
    }

    psum += __shfl_xor(psum, 16);
    psum += __shfl_xor(psum, 32);
    if (lane < 16)
        lsum_g[(size_t)half * (BH_ * S_) + (size_t)bh * S_ + q0 + lr] = psum;
}

// ---------------- attn part 2: normalized P stream + PV over a kv half ----------------
// 1024 blocks x 512 thr: (bh, qtile, half). X partials (f32) to Xp[half].
__global__ __launch_bounds__(512, 6) void attn_main(const bf16* __restrict__ Qw,
                                                    const bf16* __restrict__ Kh,
                                                    const bf16* __restrict__ Vt,
                                                    const int* __restrict__ mask,
                                                    const float* __restrict__ lsum_g,
                                                    float* __restrict__ attn_out,
                                                    float* __restrict__ Xp) {
    __shared__ __align__(16) float negf[S_ / 2];  // 4 KB
    __shared__ __align__(16) bf16 Kst[2][4096];   // 16 KB
    __shared__ __align__(16) bf16 Vst[2][4096];   // 16 KB

    const int tid = threadIdx.x;
    const int lane = tid & 63, wave = tid >> 6;
    const int lr = lane & 15, kg = lane >> 4;

    const int wg = blockIdx.x;                    // 1024 blocks, 8-XCD bijective swizzle
    const int flat = (wg & 7) * 128 + (wg >> 3);
    const int half = flat & 1;
    const int qtile = (flat >> 1) & 15;
    const int bh = flat >> 5;
    const int b = bh >> 4;
    const int q0 = qtile * 128 + wave * 16;
    const int kv0 = half * (S_ / 2);

    const bf16* Qh = Qw + (size_t)bh * S_ * HD_;
    const bf16* Kb = Kh + (size_t)bh * S_ * HD_;
    const bf16* Vb = Vt + (size_t)bh * HD_ * S_;
    const int*  mb = mask + b * S_ + kv0;
    float* arow = attn_out + (size_t)bh * S_ * S_ + kv0;

    for (int t = tid; t < S_ / 2; t += 512)
        negf[t] = mb[t] ? 0.f : NEGB_;

    const int srow = tid >> 3;                    // 0..63
    const int sch  = tid & 7;                     // 0..7
    const int sdst = swadr(srow, sch);

    bf16x8 a0 = *(const bf16x8*)(Qh + (size_t)(q0 + lr) * HD_ + kg * 8);
    bf16x8 a1 = *(const bf16x8*)(Qh + (size_t)(q0 + lr) * HD_ + 32 + kg * 8);
    const size_t lidx = (size_t)bh * S_ + q0 + lr;
    const float lg2l = __log2f(lsum_g[lidx] + lsum_g[(size_t)BH_ * S_ + lidx]);

    const int addrA = (lr + (((kg << 1)    ) & 3) * 16) << 2;
    const int addrB = (lr + (((kg << 1) | 1) & 3) * 16) << 2;
    const bool lt2 = kg < 2;

    __syncthreads();   // negf ready

    bf16x8 kreg = *(const bf16x8*)(Kb + (size_t)(kv0 + srow) * HD_ + sch * 8);
    bf16x8 vreg = *(const bf16x8*)(Vb + (size_t)srow * S_ + kv0 + sch * 8);

    f32x4 X[4] = {};
    for (int t = 0; t < 16; ++t) {
        const int buf = t & 1;
        *(bf16x8*)((char*)Kst[buf] + sdst) = kreg;
        *(bf16x8*)((char*)Vst[buf] + sdst) = vreg;
        if (t + 1 < 16) {
            kreg = *(const bf16x8*)(Kb + (size_t)(kv0 + (t + 1) * 64 + srow) * HD_ + sch * 8);
            vreg = *(const bf16x8*)(Vb + (size_t)srow * S_ + kv0 + (t + 1) * 64 + sch * 8);
        }
        barrier_lds();
        const bf16* kb = Kst[buf];
        const bf16* vb = Vst[buf];
        #pragma unroll
        for (int s2 = 0; s2 < 2; ++s2) {
            const int rlo = s2 * 32 + lr, rhi = s2 * 32 + 16 + lr;
            bf16x8 k0a = lds8(kb, rlo, kg);
            bf16x8 k1a = lds8(kb, rlo, 4 + kg);
            bf16x8 k0b = lds8(kb, rhi, kg);
            bf16x8 k1b = lds8(kb, rhi, 4 + kg);
            f32x4 nb0 = *(const f32x4*)&negf[t * 64 + s2 * 32 + kg * 4];
            f32x4 nb1 = *(const f32x4*)&negf[t * 64 + s2 * 32 + 16 + kg * 4];
            f32x4 e0, e1;
            #pragma unroll
            for (int r = 0; r < 4; ++r) { e0[r] = nb0[r] - lg2l; e1[r] = nb1[r] - lg2l; }
            e0 = mfma16(k0a, a0, e0);
            e0 = mfma16(k1a, a1, e0);
            e1 = mfma16(k0b, a0, e1);
            e1 = mfma16(k1b, a1, e1);
            f32x4 p0, p1;
            #pragma unroll
            for (int r = 0; r < 4; ++r) { p0[r] = exp2f(e0[r]); p1[r] = exp2f(e1[r]); }
            *(f32x4*)(arow + (size_t)(q0 + lr) * S_ + t * 64 + s2 * 32 + kg * 4) = p0;
            *(f32x4*)(arow + (size_t)(q0 + lr) * S_ + t * 64 + s2 * 32 + 16 + kg * 4) = p1;
            // PV: transpose P into A-frag layout via bpermute
            int q0d = pack2(p0[0], p0[1]);
            int q1d = pack2(p0[2], p0[3]);
            int q2d = pack2(p1[0], p1[1]);
            int q3d = pack2(p1[2], p1[3]);
            int bA0 = __builtin_amdgcn_ds_bpermute(addrA, q0d);
            int bA1 = __builtin_amdgcn_ds_bpermute(addrA, q1d);
            int bA2 = __builtin_amdgcn_ds_bpermute(addrA, q2d);
            int bA3 = __builtin_amdgcn_ds_bpermute(addrA, q3d);
            int bB0 = __builtin_amdgcn_ds_bpermute(addrB, q0d);
            int bB1 = __builtin_amdgcn_ds_bpermute(addrB, q1d);
            int bB2 = __builtin_amdgcn_ds_bpermute(addrB, q2d);
            int bB3 = __builtin_amdgcn_ds_bpermute(addrB, q3d);
            union { int d[4]; bf16x8 v; } pau;
            pau.d[0] = lt2 ? bA0 : bA2;
            pau.d[1] = lt2 ? bA1 : bA3;
            pau.d[2] = lt2 ? bB0 : bB2;
            pau.d[3] = lt2 ? bB1 : bB3;
            #pragma unroll
            for (int ds = 0; ds < 4; ++ds) {
                bf16x8 v = lds8(vb, ds * 16 + lr, s2 * 4 + kg);
                X[ds] = mfma16(v, pau.v, X[ds]);   // X[d=kg*4+r][q=lr], normalized
            }
        }
        barrier_lds();
    }

    // store f32 X partial: Xp[half][bh][q][d]
    float* xrow = Xp + ((size_t)half * BH_ + bh) * S_ * 64 + (size_t)(q0 + lr) * 64;
    #pragma unroll
    for (int ds = 0; ds < 4; ++ds)
        *(f32x4*)(xrow + ds * 16 + kg * 4) = X[ds];
}

// ---------------- merge X halves: Xh[b][s][h*64+d] = bf16(Xp[0]+Xp[1]) ----------------
__global__ __launch_bounds__(256) void merge_x(const float* __restrict__ Xp,
                                               bf16* __restrict__ Xh) {
    const int g = blockIdx.x * 256 + threadIdx.x;   // 0..524287, 8 elems each
    const int d0 = (g & 7) * 8;
    const int hs = g >> 3;                          // (b*2048+s)*16 + h
    const int h = hs & 15;
    const int m = hs >> 4;                          // b*2048+s
    const int b = m >> 11, s = m & 2047;
    const size_t pbase = ((size_t)(b * NH_ + h)) * S_ * 64 + (size_t)s * 64 + d0;
    f32x4 x0a = *(const f32x4*)(Xp + pbase);
    f32x4 x0b = *(const f32x4*)(Xp + pbase + 4);
    f32x4 x1a = *(const f32x4*)(Xp + (size_t)BH_ * S_ * 64 + pbase);
    f32x4 x1b = *(const f32x4*)(Xp + (size_t)BH_ * S_ * 64 + pbase + 4);
    bf16x8 o;
    #pragma unroll
    for (int r = 0; r < 4; ++r) {
        o[r]     = (bf16)(x0a[r] + x1a[r]);
        o[4 + r] = (bf16)(x0b[r] + x1b[r]);
    }
    *(bf16x8*)(Xh + (size_t)m * HID_ + h * 64 + d0) = o;
}

// ---------------- output projection: LDS-staged GEMM, BM=128 BN=64 BK=64 ----------------
__global__ __launch_bounds__(256, 3) void out_gemm(const bf16* __restrict__ X,
                                                   const bf16* __restrict__ Wo,
                                                   const float* __restrict__ bo,
                                                   float* __restrict__ out) {
    __shared__ __align__(16) bf16 Ast[2][128 * 64];
    __shared__ __align__(16) bf16 Wst[2][64 * 64];

    const int tid = threadIdx.x;
    const int wave = tid >> 6, lane = tid & 63;
    const int lr = lane & 15, kg = lane >> 4;
    const int mb0 = blockIdx.x * 128;
    const int n0 = blockIdx.y * 64;

    const int arow = tid >> 1, akc = (tid & 1) * 32;
    const int wrow = tid >> 2, wkc = (tid & 3) * 16;

    bf16x8 ar[4];
    bf16x8 wr[2];
    auto loadT = [&](int k0) {
        const bf16* ap = X + (size_t)(mb0 + arow) * HID_ + k0 + akc;
        #pragma unroll
        for (int j = 0; j < 4; ++j) ar[j] = *(const bf16x8*)(ap + j * 8);
        const bf16* wp = Wo + (size_t)(n0 + wrow) * HID_ + k0 + wkc;
        wr[0] = *(const bf16x8*)wp;
        wr[1] = *(const bf16x8*)(wp + 8);
    };
    auto writeT = [&](int buf) {
        #pragma unroll
        for (int c = 0; c < 4; ++c)
            *(bf16x8*)((char*)Ast[buf] + swadr(arow, (akc >> 3) + c)) = ar[c];
        *(bf16x8*)((char*)Wst[buf] + swadr(wrow, wkc >> 3)) = wr[0];
        *(bf16x8*)((char*)Wst[buf] + swadr(wrow, (wkc >> 3) + 1)) = wr[1];
    };

    f32x4 acc[2][4] = {};
    loadT(0);
    for (int t = 0; t < 16; ++t) {
        const int buf = t & 1;
        writeT(buf);
        if (t < 15) loadT((t + 1) * 64);
        barrier_lds();
        const bf16* ab = Ast[buf];
        const bf16* wb = Wst[buf];
        #pragma unroll
        for (int kp = 0; kp < 2; ++kp) {
            bf16x8 af0 = lds8(ab, wave * 16 + lr, kp * 4 + kg);
            bf16x8 af1 = lds8(ab, 64 + wave * 16 + lr, kp * 4 + kg);
            #pragma unroll
            for (int nf = 0; nf < 4; ++nf) {
                bf16x8 wf = lds8(wb, nf * 16 + lr, kp * 4 + kg);
                acc[0][nf] = mfma16(af0, wf, acc[0][nf]);
                acc[1][nf] = mfma16(af1, wf, acc[1][nf]);
            }
        }
        barrier_lds();
    }

    const int m_base = mb0 + wave * 16;
    #pragma unroll
    for (int t = 0; t < 2; ++t) {
        #pragma unroll
        for (int cg = 0; cg < 4; ++cg) {
            int col = n0 + cg * 16 + lr;
            float bv = bo[col];
            #pragma unroll
            for (int r = 0; r < 4; ++r)
                out[(size_t)(m_base + t * 64 + kg * 4 + r) * HID_ + col] = acc[t][cg][r] + bv;
        }
    }
}

// ---------------- launch ----------------
extern "C" void kernel_launch(void* const* d_in, const int* in_sizes, int n_in,
                              void* d_out, int out_size, void* d_ws, size_t ws_size,
                              hipStream_t stream) {
    const float* query = (const float*)d_in[0];
    const float* key_  = (const float*)d_in[1];
    const float* value = (const float*)d_in[2];
    const int*   mask  = (const int*)d_in[3];
    const float* Wq = (const float*)d_in[4];
    const float* bq = (const float*)d_in[5];
    const float* Wk = (const float*)d_in[6];
    const float* bk = (const float*)d_in[7];
    const float* Wv = (const float*)d_in[8];
    const float* bv = (const float*)d_in[9];
    const float* Ww = (const float*)d_in[10];
    const float* bw = (const float*)d_in[11];
    const float* Wo = (const float*)d_in[12];
    const float* bo = (const float*)d_in[13];
    float* out = (float*)d_out;

    char* ws = (char*)d_ws;
    size_t off = 0;
    auto alloc = [&](size_t bytes) {
        void* p = ws + off;
        off += (bytes + 255) & ~(size_t)255;
        return p;
    };
    bf16*  Wq_eff = (bf16*)alloc((size_t)HID_ * HID_ * 2);
    float* bq_eff = (float*)alloc((size_t)HID_ * 4);
    bf16*  Wk_b   = (bf16*)alloc((size_t)HID_ * HID_ * 2);
    bf16*  Wv_b   = (bf16*)alloc((size_t)HID_ * HID_ * 2);
    bf16*  Wo_b   = (bf16*)alloc((size_t)HID_ * HID_ * 2);
    bf16*  Qw     = (bf16*)alloc((size_t)M_ * HID_ * 2);   // [B][H][S][D], pre-scaled log2e
    bf16*  Kh     = (bf16*)alloc((size_t)M_ * HID_ * 2);   // [B][H][S][D]
    bf16*  Vt     = (bf16*)alloc((size_t)M_ * HID_ * 2);   // [B][H][D][S]
    bf16*  Xh     = (bf16*)alloc((size_t)M_ * HID_ * 2);   // [B][S][HID]
    float* lsum_g = (float*)alloc((size_t)2 * BH_ * S_ * 4);    // 512 KB partial sums
    float* Xp     = (float*)alloc((size_t)2 * BH_ * S_ * 64 * 4); // 32 MB X partials
    (void)ws_size; (void)in_sizes; (void)n_in; (void)out_size;

    dim3 gcast(1024, 3);
    cast3<<<gcast, 256, 0, stream>>>(Wk, Wv, Wo, Wk_b, Wv_b, Wo_b);
    fuse_wq<<<64, 256, 0, stream>>>(Ww, Wq, bq, bw, Wq_eff, bq_eff);

    dim3 gproj(M_ / 128, HID_ / 128, 3);  // (32,8,3)
    proj3<<<gproj, 256, 0, stream>>>(query, key_, value,
                                     Wq_eff, Wk_b, Wv_b,
                                     bq_eff, bk, bv,
                                     Qw, Kh, Vt);

    attn_sums<<<1024, 512, 0, stream>>>(Qw, Kh, mask, lsum_g);
    attn_main<<<1024, 512, 0, stream>>>(Qw, Kh, Vt, mask, lsum_g, out + X_ELEMS, Xp);
    merge_x<<<2048, 256, 0, stream>>>(Xp, Xh);

    dim3 gout(M_ / 128, HID_ / 64);      // (32,16)
    out_gemm<<<gout, 256, 0, stream>>>(Xh, Wo_b, bo, out);
}

// Round 16
// 329.917 us; speedup vs baseline: 1.0403x; 1.0403x over previous
//
#include <hip/hip_runtime.h>
#include <hip/hip_bf16.h>

// B=2, S=2048, HID=1024, NH=16, HD=64
#define B_    2
#define S_    2048
#define HID_  1024
#define NH_   16
#define HD_   64
#define M_    (B_ * S_)          // 4096 rows
#define NEGB_ (-1.0e30f)         // mask bias in log2 domain; exp2 -> 0
#define LOG2E 1.44269504088896340736f
#define X_ELEMS 4194304          // B*S*HID

typedef __bf16 bf16;
typedef bf16  bf16x2 __attribute__((ext_vector_type(2)));
typedef bf16  bf16x4 __attribute__((ext_vector_type(4)));
typedef bf16  bf16x8 __attribute__((ext_vector_type(8)));
typedef float f32x4  __attribute__((ext_vector_type(4)));

static __device__ __forceinline__ f32x4 mfma16(bf16x8 a, bf16x8 b, f32x4 c) {
    return __builtin_amdgcn_mfma_f32_16x16x32_bf16(a, b, c, 0, 0, 0);
}

static __device__ __forceinline__ int pack2(float x, float y) {
    union { bf16x2 h; int i; } u;
    u.h = bf16x2{(bf16)x, (bf16)y};
    return u.i;
}

// LDS-only barrier: drains ds ops (staging-write visibility) but leaves
// global stores/loads in flight across the barrier.
static __device__ __forceinline__ void barrier_lds() {
    asm volatile("s_waitcnt lgkmcnt(0)" ::: "memory");
    __builtin_amdgcn_s_barrier();
}

// swizzled LDS byte address for [row][chunk16B] tiles with 128B row stride
static __device__ __forceinline__ int swadr(int row, int chunk) {
    return row * 128 + ((chunk ^ (row & 7)) << 4);
}
static __device__ __forceinline__ bf16x8 lds8(const bf16* base, int row, int chunk) {
    return *(const bf16x8*)((const char*)base + swadr(row, chunk));
}

// ---------------- prep kernels ----------------

__global__ void cast3(const float* __restrict__ a, const float* __restrict__ b,
                      const float* __restrict__ c, bf16* __restrict__ oa,
                      bf16* __restrict__ ob, bf16* __restrict__ oc) {
    const float* in = blockIdx.y == 0 ? a : blockIdx.y == 1 ? b : c;
    bf16* out = blockIdx.y == 0 ? oa : blockIdx.y == 1 ? ob : oc;
    int i = (blockIdx.x * 256 + threadIdx.x) * 4;
    float4 v = *(const float4*)(in + i);
    out[i + 0] = (bf16)v.x;
    out[i + 1] = (bf16)v.y;
    out[i + 2] = (bf16)v.z;
    out[i + 3] = (bf16)v.w;
}

// Wq_eff[h*64+j][i] = LOG2E * sum_d Ww[j][d] * Wq[h*64+d][i]; also bq_eff.
__global__ __launch_bounds__(256) void fuse_wq(const float* __restrict__ Ww,
                                               const float* __restrict__ Wq,
                                               const float* __restrict__ bq,
                                               const float* __restrict__ bw,
                                               bf16* __restrict__ Wq_eff,
                                               float* __restrict__ bq_eff) {
    __shared__ float ww[64][64];
    const int h = blockIdx.x >> 2, chunk = blockIdx.x & 3;
    const int i = chunk * 256 + threadIdx.x;
    for (int t = threadIdx.x; t < 4096; t += 256) ww[t >> 6][t & 63] = Ww[t];
    __syncthreads();
    float col[64];
    #pragma unroll
    for (int d = 0; d < 64; ++d) col[d] = Wq[(size_t)(h * 64 + d) * 1024 + i];
    for (int j = 0; j < 64; ++j) {
        float acc = 0.f;
        #pragma unroll
        for (int d = 0; d < 64; ++d) acc += ww[j][d] * col[d];
        Wq_eff[(size_t)(h * 64 + j) * 1024 + i] = (bf16)(acc * LOG2E);
    }
    if (chunk == 0 && threadIdx.x < 64) {
        int j = threadIdx.x;
        float acc = bw[j];
        for (int d = 0; d < 64; ++d) acc += ww[j][d] * bq[h * 64 + d];
        bq_eff[h * 64 + j] = acc * LOG2E;
    }
}

// ---------------- QKV projections: LDS-staged GEMM, BM=128 BN=128 BK=64 ----------------
__global__ __launch_bounds__(256, 2) void proj3(const float* __restrict__ Aq,
                                                const float* __restrict__ Ak,
                                                const float* __restrict__ Av,
                                                const bf16* __restrict__ W0,
                                                const bf16* __restrict__ W1,
                                                const bf16* __restrict__ W2,
                                                const float* __restrict__ b0,
                                                const float* __restrict__ b1,
                                                const float* __restrict__ b2,
                                                bf16* __restrict__ Qw,
                                                bf16* __restrict__ Kh,
                                                bf16* __restrict__ Vt) {
    __shared__ __align__(16) bf16 Ast[2][128 * 64];   // 2 x 16 KB
    __shared__ __align__(16) bf16 Wst[2][128 * 64];   // 2 x 16 KB
    const int z = blockIdx.z;
    const float* A = z == 0 ? Aq : z == 1 ? Ak : Av;
    const bf16* W = z == 0 ? W0 : z == 1 ? W1 : W2;
    const float* bias = z == 0 ? b0 : z == 1 ? b1 : b2;

    const int tid = threadIdx.x;
    const int wave = tid >> 6, lane = tid & 63;
    const int lr = lane & 15, kg = lane >> 4;
    const int mb0 = blockIdx.x * 128;
    const int n0 = blockIdx.y * 128;

    const int arow = tid >> 1, akc = (tid & 1) * 32;   // A: 128 rows x 2 half-rows (f32)
    const int wrow = tid >> 1, wkc = (tid & 1) * 32;   // W: 128 rows x 2 half-rows (bf16)

    float4 ar[8];
    bf16x8 wr[4];
    auto loadT = [&](int k0) {
        const float4* ap = (const float4*)(A + (size_t)(mb0 + arow) * HID_ + k0 + akc);
        #pragma unroll
        for (int j = 0; j < 8; ++j) ar[j] = ap[j];
        const bf16* wp = W + (size_t)(n0 + wrow) * HID_ + k0 + wkc;
        #pragma unroll
        for (int j = 0; j < 4; ++j) wr[j] = *(const bf16x8*)(wp + j * 8);
    };
    auto writeT = [&](int buf) {
        #pragma unroll
        for (int c = 0; c < 4; ++c) {
            float4 x0 = ar[2 * c], x1 = ar[2 * c + 1];
            bf16x8 v;
            v[0] = (bf16)x0.x; v[1] = (bf16)x0.y; v[2] = (bf16)x0.z; v[3] = (bf16)x0.w;
            v[4] = (bf16)x1.x; v[5] = (bf16)x1.y; v[6] = (bf16)x1.z; v[7] = (bf16)x1.w;
            *(bf16x8*)((char*)Ast[buf] + swadr(arow, (akc >> 3) + c)) = v;
        }
        #pragma unroll
        for (int c = 0; c < 4; ++c)
            *(bf16x8*)((char*)Wst[buf] + swadr(wrow, (wkc >> 3) + c)) = wr[c];
    };

    f32x4 acc[2][8] = {};
    loadT(0);
    for (int t = 0; t < 16; ++t) {
        const int buf = t & 1;
        writeT(buf);
        if (t < 15) loadT((t + 1) * 64);
        barrier_lds();
        const bf16* ab = Ast[buf];
        const bf16* wb = Wst[buf];
        #pragma unroll
        for (int kp = 0; kp < 2; ++kp) {
            bf16x8 af0 = lds8(ab, wave * 16 + lr, kp * 4 + kg);
            bf16x8 af1 = lds8(ab, 64 + wave * 16 + lr, kp * 4 + kg);
            #pragma unroll
            for (int nf = 0; nf < 8; ++nf) {
                bf16x8 wf = lds8(wb, nf * 16 + lr, kp * 4 + kg);
                acc[0][nf] = mfma16(af0, wf, acc[0][nf]);
                acc[1][nf] = mfma16(af1, wf, acc[1][nf]);
            }
        }
        barrier_lds();
    }

    const int m_base = mb0 + wave * 16;
    #pragma unroll
    for (int t = 0; t < 2; ++t) {
        #pragma unroll
        for (int cg = 0; cg < 8; ++cg) {
            int col = n0 + cg * 16 + lr;
            float bv = bias[col];
            int h = col >> 6, d = col & 63;
            #pragma unroll
            for (int r = 0; r < 4; ++r) {
                int m = m_base + t * 64 + kg * 4 + r;
                int b = m >> 11, s = m & 2047;
                float val = acc[t][cg][r] + bv;
                if (z == 0)
                    Qw[((size_t)(b * NH_ + h) * S_ + s) * HD_ + d] = (bf16)val;
                else if (z == 1)
                    Kh[((size_t)(b * NH_ + h) * S_ + s) * HD_ + d] = (bf16)val;
                else
                    Vt[((size_t)(b * NH_ + h) * HD_ + d) * S_ + s] = (bf16)val;
            }
        }
    }
}

// ---------------- attn part 1: row sums only (QK^T + exp2 + reduce) ----------------
// 512 blocks x 512 thr (8 waves x 16 q = 128 q/block). K staged once per 128 q.
__global__ __launch_bounds__(512, 4) void attn_sums(const bf16* __restrict__ Qw,
                                                    const bf16* __restrict__ Kh,
                                                    const int* __restrict__ mask,
                                                    float* __restrict__ lsum_g) {
    __shared__ __align__(16) float negf[S_];      // 8 KB
    __shared__ __align__(16) bf16 Kst[2][4096];   // 16 KB

    const int tid = threadIdx.x;
    const int lane = tid & 63, wave = tid >> 6;
    const int lr = lane & 15, kg = lane >> 4;

    const int wg = blockIdx.x;                    // 512 blocks, 8-XCD bijective swizzle
    const int flat = (wg & 7) * 64 + (wg >> 3);
    const int qtile = flat & 15;
    const int bh = flat >> 4;
    const int b = bh >> 4;
    const int q0 = qtile * 128 + wave * 16;

    const bf16* Qh = Qw + (size_t)bh * S_ * HD_;
    const bf16* Kb = Kh + (size_t)bh * S_ * HD_;
    const int*  mb = mask + b * S_;

    for (int t = tid; t < S_; t += 512)
        negf[t] = mb[t] ? 0.f : NEGB_;

    const int srow = tid >> 3;                    // 0..63
    const int sch  = tid & 7;                     // 0..7
    const int sdst = swadr(srow, sch);

    bf16x8 a0 = *(const bf16x8*)(Qh + (size_t)(q0 + lr) * HD_ + kg * 8);
    bf16x8 a1 = *(const bf16x8*)(Qh + (size_t)(q0 + lr) * HD_ + 32 + kg * 8);

    __syncthreads();   // negf ready

    bf16x8 kreg = *(const bf16x8*)(Kb + (size_t)srow * HD_ + sch * 8);

    float psum = 0.f;
    for (int t = 0; t < 32; ++t) {
        const int buf = t & 1;
        *(bf16x8*)((char*)Kst[buf] + sdst) = kreg;
        if (t + 1 < 32)
            kreg = *(const bf16x8*)(Kb + (size_t)((t + 1) * 64 + srow) * HD_ + sch * 8);
        barrier_lds();
        const bf16* kb = Kst[buf];
        __builtin_amdgcn_s_setprio(1);
        #pragma unroll
        for (int s2 = 0; s2 < 2; ++s2) {
            const int rlo = s2 * 32 + lr, rhi = s2 * 32 + 16 + lr;
            bf16x8 k0a = lds8(kb, rlo, kg);
            bf16x8 k1a = lds8(kb, rlo, 4 + kg);
            bf16x8 k0b = lds8(kb, rhi, kg);
            bf16x8 k1b = lds8(kb, rhi, 4 + kg);
            f32x4 e0 = *(const f32x4*)&negf[t * 64 + s2 * 32 + kg * 4];
            f32x4 e1 = *(const f32x4*)&negf[t * 64 + s2 * 32 + 16 + kg * 4];
            e0 = mfma16(k0a, a0, e0);
            e0 = mfma16(k1a, a1, e0);
            e1 = mfma16(k0b, a0, e1);
            e1 = mfma16(k1b, a1, e1);
            #pragma unroll
            for (int r = 0; r < 4; ++r)
                psum += exp2f(e0[r]) + exp2f(e1[r]);
        }
        __builtin_amdgcn_s_setprio(0);
        barrier_lds();
    }

    psum += __shfl_xor(psum, 16);
    psum += __shfl_xor(psum, 32);
    if (lane < 16) lsum_g[(size_t)bh * S_ + q0 + lr] = psum;
}

// ---------------- attn part 2: normalized P stream + PV, one sweep ----------------
// 512 blocks x 512 thr (8 waves x 16 q). C-init = negb - lg2l so exp2 gives
// final P; LDS-only loop barriers keep HBM stores in flight across iterations.
__global__ __launch_bounds__(512, 4) void attn_main(const bf16* __restrict__ Qw,
                                                    const bf16* __restrict__ Kh,
                                                    const bf16* __restrict__ Vt,
                                                    const int* __restrict__ mask,
                                                    const float* __restrict__ lsum_g,
                                                    float* __restrict__ attn_out,
                                                    bf16* __restrict__ Xh) {
    __shared__ __align__(16) float negf[S_];      // 8 KB
    __shared__ __align__(16) bf16 Kst[2][4096];   // 16 KB
    __shared__ __align__(16) bf16 Vst[2][4096];   // 16 KB

    const int tid = threadIdx.x;
    const int lane = tid & 63, wave = tid >> 6;
    const int lr = lane & 15, kg = lane >> 4;

    const int wg = blockIdx.x;                    // 512 blocks, 8-XCD bijective swizzle
    const int flat = (wg & 7) * 64 + (wg >> 3);
    const int qtile = flat & 15;
    const int bh = flat >> 4;
    const int b = bh >> 4, h = bh & 15;
    const int q0 = qtile * 128 + wave * 16;

    const bf16* Qh = Qw + (size_t)bh * S_ * HD_;
    const bf16* Kb = Kh + (size_t)bh * S_ * HD_;
    const bf16* Vb = Vt + (size_t)bh * HD_ * S_;
    const int*  mb = mask + b * S_;
    float* arow = attn_out + (size_t)bh * S_ * S_;

    for (int t = tid; t < S_; t += 512)
        negf[t] = mb[t] ? 0.f : NEGB_;

    const int srow = tid >> 3;                    // 0..63
    const int sch  = tid & 7;                     // 0..7
    const int sdst = swadr(srow, sch);

    bf16x8 a0 = *(const bf16x8*)(Qh + (size_t)(q0 + lr) * HD_ + kg * 8);
    bf16x8 a1 = *(const bf16x8*)(Qh + (size_t)(q0 + lr) * HD_ + 32 + kg * 8);
    const float lg2l = __log2f(lsum_g[(size_t)bh * S_ + q0 + lr]);

    const int addrA = (lr + (((kg << 1)    ) & 3) * 16) << 2;
    const int addrB = (lr + (((kg << 1) | 1) & 3) * 16) << 2;
    const bool lt2 = kg < 2;

    __syncthreads();   // negf ready

    bf16x8 kreg = *(const bf16x8*)(Kb + (size_t)srow * HD_ + sch * 8);
    bf16x8 vreg = *(const bf16x8*)(Vb + (size_t)srow * S_ + sch * 8);

    f32x4 X[4] = {};
    for (int t = 0; t < 32; ++t) {
        const int buf = t & 1;
        *(bf16x8*)((char*)Kst[buf] + sdst) = kreg;
        *(bf16x8*)((char*)Vst[buf] + sdst) = vreg;
        if (t + 1 < 32) {
            kreg = *(const bf16x8*)(Kb + (size_t)((t + 1) * 64 + srow) * HD_ + sch * 8);
            vreg = *(const bf16x8*)(Vb + (size_t)srow * S_ + (t + 1) * 64 + sch * 8);
        }
        barrier_lds();
        const bf16* kb = Kst[buf];
        const bf16* vb = Vst[buf];
        __builtin_amdgcn_s_setprio(1);
        #pragma unroll
        for (int s2 = 0; s2 < 2; ++s2) {
            const int rlo = s2 * 32 + lr, rhi = s2 * 32 + 16 + lr;
            bf16x8 k0a = lds8(kb, rlo, kg);
            bf16x8 k1a = lds8(kb, rlo, 4 + kg);
            bf16x8 k0b = lds8(kb, rhi, kg);
            bf16x8 k1b = lds8(kb, rhi, 4 + kg);
            f32x4 nb0 = *(const f32x4*)&negf[t * 64 + s2 * 32 + kg * 4];
            f32x4 nb1 = *(const f32x4*)&negf[t * 64 + s2 * 32 + 16 + kg * 4];
            f32x4 e0, e1;
            #pragma unroll
            for (int r = 0; r < 4; ++r) { e0[r] = nb0[r] - lg2l; e1[r] = nb1[r] - lg2l; }
            e0 = mfma16(k0a, a0, e0);
            e0 = mfma16(k1a, a1, e0);
            e1 = mfma16(k0b, a0, e1);
            e1 = mfma16(k1b, a1, e1);
            f32x4 p0, p1;
            #pragma unroll
            for (int r = 0; r < 4; ++r) { p0[r] = exp2f(e0[r]); p1[r] = exp2f(e1[r]); }
            // store normalized P: rows q0+lr, cols t*64+s2*32+kg*4 (and +16)
            *(f32x4*)(arow + (size_t)(q0 + lr) * S_ + t * 64 + s2 * 32 + kg * 4) = p0;
            *(f32x4*)(arow + (size_t)(q0 + lr) * S_ + t * 64 + s2 * 32 + 16 + kg * 4) = p1;
            // PV: transpose P into A-frag layout via bpermute
            int q0d = pack2(p0[0], p0[1]);
            int q1d = pack2(p0[2], p0[3]);
            int q2d = pack2(p1[0], p1[1]);
            int q3d = pack2(p1[2], p1[3]);
            int bA0 = __builtin_amdgcn_ds_bpermute(addrA, q0d);
            int bA1 = __builtin_amdgcn_ds_bpermute(addrA, q1d);
            int bA2 = __builtin_amdgcn_ds_bpermute(addrA, q2d);
            int bA3 = __builtin_amdgcn_ds_bpermute(addrA, q3d);
            int bB0 = __builtin_amdgcn_ds_bpermute(addrB, q0d);
            int bB1 = __builtin_amdgcn_ds_bpermute(addrB, q1d);
            int bB2 = __builtin_amdgcn_ds_bpermute(addrB, q2d);
            int bB3 = __builtin_amdgcn_ds_bpermute(addrB, q3d);
            union { int d[4]; bf16x8 v; } pau;
            pau.d[0] = lt2 ? bA0 : bA2;
            pau.d[1] = lt2 ? bA1 : bA3;
            pau.d[2] = lt2 ? bB0 : bB2;
            pau.d[3] = lt2 ? bB1 : bB3;
            #pragma unroll
            for (int ds = 0; ds < 4; ++ds) {
                bf16x8 v = lds8(vb, ds * 16 + lr, s2 * 4 + kg);
                X[ds] = mfma16(v, pau.v, X[ds]);   // X[d=kg*4+r][q=lr], normalized
            }
        }
        __builtin_amdgcn_s_setprio(0);
        barrier_lds();
    }

    bf16* xrow = Xh + ((size_t)(b * S_ + q0 + lr)) * HID_ + h * HD_;
    #pragma unroll
    for (int ds = 0; ds < 4; ++ds) {
        bf16x4 xv;
        #pragma unroll
        for (int r = 0; r < 4; ++r) xv[r] = (bf16)X[ds][r];
        *(bf16x4*)(xrow + ds * 16 + kg * 4) = xv;
    }
}

// ---------------- output projection: LDS-staged GEMM, BM=128 BN=64 BK=64 ----------------
__global__ __launch_bounds__(256, 3) void out_gemm(const bf16* __restrict__ X,
                                                   const bf16* __restrict__ Wo,
                                                   const float* __restrict__ bo,
                                                   float* __restrict__ out) {
    __shared__ __align__(16) bf16 Ast[2][128 * 64];
    __shared__ __align__(16) bf16 Wst[2][64 * 64];

    const int tid = threadIdx.x;
    const int wave = tid >> 6, lane = tid & 63;
    const int lr = lane & 15, kg = lane >> 4;
    const int mb0 = blockIdx.x * 128;
    const int n0 = blockIdx.y * 64;

    const int arow = tid >> 1, akc = (tid & 1) * 32;
    const int wrow = tid >> 2, wkc = (tid & 3) * 16;

    bf16x8 ar[4];
    bf16x8 wr[2];
    auto loadT = [&](int k0) {
        const bf16* ap = X + (size_t)(mb0 + arow) * HID_ + k0 + akc;
        #pragma unroll
        for (int j = 0; j < 4; ++j) ar[j] = *(const bf16x8*)(ap + j * 8);
        const bf16* wp = Wo + (size_t)(n0 + wrow) * HID_ + k0 + wkc;
        wr[0] = *(const bf16x8*)wp;
        wr[1] = *(const bf16x8*)(wp + 8);
    };
    auto writeT = [&](int buf) {
        #pragma unroll
        for (int c = 0; c < 4; ++c)
            *(bf16x8*)((char*)Ast[buf] + swadr(arow, (akc >> 3) + c)) = ar[c];
        *(bf16x8*)((char*)Wst[buf] + swadr(wrow, wkc >> 3)) = wr[0];
        *(bf16x8*)((char*)Wst[buf] + swadr(wrow, (wkc >> 3) + 1)) = wr[1];
    };

    f32x4 acc[2][4] = {};
    loadT(0);
    for (int t = 0; t < 16; ++t) {
        const int buf = t & 1;
        writeT(buf);
        if (t < 15) loadT((t + 1) * 64);
        barrier_lds();
        const bf16* ab = Ast[buf];
        const bf16* wb = Wst[buf];
        #pragma unroll
        for (int kp = 0; kp < 2; ++kp) {
            bf16x8 af0 = lds8(ab, wave * 16 + lr, kp * 4 + kg);
            bf16x8 af1 = lds8(ab, 64 + wave * 16 + lr, kp * 4 + kg);
            #pragma unroll
            for (int nf = 0; nf < 4; ++nf) {
                bf16x8 wf = lds8(wb, nf * 16 + lr, kp * 4 + kg);
                acc[0][nf] = mfma16(af0, wf, acc[0][nf]);
                acc[1][nf] = mfma16(af1, wf, acc[1][nf]);
            }
        }
        barrier_lds();
    }

    const int m_base = mb0 + wave * 16;
    #pragma unroll
    for (int t = 0; t < 2; ++t) {
        #pragma unroll
        for (int cg = 0; cg < 4; ++cg) {
            int col = n0 + cg * 16 + lr;
            float bv = bo[col];
            #pragma unroll
            for (int r = 0; r < 4; ++r)
                out[(size_t)(m_base + t * 64 + kg * 4 + r) * HID_ + col] = acc[t][cg][r] + bv;
        }
    }
}

// ---------------- launch ----------------
extern "C" void kernel_launch(void* const* d_in, const int* in_sizes, int n_in,
                              void* d_out, int out_size, void* d_ws, size_t ws_size,
                              hipStream_t stream) {
    const float* query = (const float*)d_in[0];
    const float* key_  = (const float*)d_in[1];
    const float* value = (const float*)d_in[2];
    const int*   mask  = (const int*)d_in[3];
    const float* Wq = (const float*)d_in[4];
    const float* bq = (const float*)d_in[5];
    const float* Wk = (const float*)d_in[6];
    const float* bk = (const float*)d_in[7];
    const float* Wv = (const float*)d_in[8];
    const float* bv = (const float*)d_in[9];
    const float* Ww = (const float*)d_in[10];
    const float* bw = (const float*)d_in[11];
    const float* Wo = (const float*)d_in[12];
    const float* bo = (const float*)d_in[13];
    float* out = (float*)d_out;

    char* ws = (char*)d_ws;
    size_t off = 0;
    auto alloc = [&](size_t bytes) {
        void* p = ws + off;
        off += (bytes + 255) & ~(size_t)255;
        return p;
    };
    bf16*  Wq_eff = (bf16*)alloc((size_t)HID_ * HID_ * 2);
    float* bq_eff = (float*)alloc((size_t)HID_ * 4);
    bf16*  Wk_b   = (bf16*)alloc((size_t)HID_ * HID_ * 2);
    bf16*  Wv_b   = (bf16*)alloc((size_t)HID_ * HID_ * 2);
    bf16*  Wo_b   = (bf16*)alloc((size_t)HID_ * HID_ * 2);
    bf16*  Qw     = (bf16*)alloc((size_t)M_ * HID_ * 2);   // [B][H][S][D], pre-scaled log2e
    bf16*  Kh     = (bf16*)alloc((size_t)M_ * HID_ * 2);   // [B][H][S][D]
    bf16*  Vt     = (bf16*)alloc((size_t)M_ * HID_ * 2);   // [B][H][D][S]
    bf16*  Xh     = (bf16*)alloc((size_t)M_ * HID_ * 2);   // [B][S][HID]
    float* lsum_g = (float*)alloc((size_t)B_ * NH_ * S_ * 4);  // 256 KB row sums
    (void)ws_size; (void)in_sizes; (void)n_in; (void)out_size;

    dim3 gcast(1024, 3);
    cast3<<<gcast, 256, 0, stream>>>(Wk, Wv, Wo, Wk_b, Wv_b, Wo_b);
    fuse_wq<<<64, 256, 0, stream>>>(Ww, Wq, bq, bw, Wq_eff, bq_eff);

    dim3 gproj(M_ / 128, HID_ / 128, 3);  // (32,8,3)
    proj3<<<gproj, 256, 0, stream>>>(query, key_, value,
                                     Wq_eff, Wk_b, Wv_b,
                                     bq_eff, bk, bv,
                                     Qw, Kh, Vt);

    attn_sums<<<512, 512, 0, stream>>>(Qw, Kh, mask, lsum_g);
    attn_main<<<512, 512, 0, stream>>>(Qw, Kh, Vt, mask, lsum_g, out + X_ELEMS, Xh);

    dim3 gout(M_ / 128, HID_ / 64);      // (32,16)
    out_gemm<<<gout, 256, 0, stream>>>(Xh, Wo_b, bo, out);
}